// Round 7
// baseline (678.287 us; speedup 1.0000x reference)
//
#include <hip/hip_runtime.h>

// =====================================================================
// GraphAutoEncoder forward (all fp32). GCN via CSR build + gather.
// R3: register-tiled fp32 GEMM. R6->R7: CSR binning rebuilt as a
// deterministic counting sort — R6 evidence: every device-scope atomic
// writes ~32B through to HBM (1.6M cursor atomics ~= 52 MB of R6's
// 65 MB WRITE_SIZE). New build has ZERO global atomics: per-block LDS
// histograms -> single-block scan (segments ordered bucket-major, then
// XCD residue, then block-group -> same-XCD segments adjacent) -> replay
// with LDS cursors, contiguous per-(block,bucket) segment writes.
// =====================================================================

constexpr int NBLK = 128;           // scatter blocks (chunk = E/128)
constexpr int GRP  = NBLK / 8;      // block-groups per XCD residue

// ---------------- GEMM: C[:,foff:foff+MT] = act(A @ W^T + b) ---------
template <int K, int MT, int M, int ACT, bool BIAS>  // ACT: 0 none,1 relu,2 sigmoid
__global__ __launch_bounds__(256) void gemm_rt(const float* __restrict__ A,
                                               const float* __restrict__ W,
                                               const float* __restrict__ bias,
                                               float* __restrict__ C, int N) {
    constexpr int KC = 32;
    constexpr int TM = MT / 16;
    constexpr int TN = 8;
    __shared__ float As[KC][128 + 4];
    __shared__ float Ws[KC][MT + 4];

    const int tid  = threadIdx.x;
    const int tx   = tid & 15;
    const int ty   = tid >> 4;
    const int nodeBase = blockIdx.x * 128;
    const int foff     = blockIdx.y * MT;

    float acc[TN][TM];
#pragma unroll
    for (int i = 0; i < TN; ++i)
#pragma unroll
        for (int j = 0; j < TM; ++j) acc[i][j] = 0.f;

    for (int kc = 0; kc < K; kc += KC) {
        __syncthreads();
#pragma unroll
        for (int i = 0; i < 4; ++i) {
            int f  = tid + 256 * i;
            int n  = f >> 3;
            int k4 = f & 7;
            int gn = nodeBase + n;
            float4 v = make_float4(0.f, 0.f, 0.f, 0.f);
            if (gn < N) v = *(const float4*)(A + (size_t)gn * K + kc + k4 * 4);
            As[k4 * 4 + 0][n] = v.x;
            As[k4 * 4 + 1][n] = v.y;
            As[k4 * 4 + 2][n] = v.z;
            As[k4 * 4 + 3][n] = v.w;
        }
#pragma unroll
        for (int i = 0; i < MT / 32; ++i) {
            int f  = tid + 256 * i;
            int m  = f >> 3;
            int k4 = f & 7;
            float4 v = *(const float4*)(W + (size_t)(foff + m) * K + kc + k4 * 4);
            Ws[k4 * 4 + 0][m] = v.x;
            Ws[k4 * 4 + 1][m] = v.y;
            Ws[k4 * 4 + 2][m] = v.z;
            Ws[k4 * 4 + 3][m] = v.w;
        }
        __syncthreads();
#pragma unroll 4
        for (int k = 0; k < KC; ++k) {
            float a[TN];
            float w[TM];
#pragma unroll
            for (int i = 0; i < TN; ++i) a[i] = As[k][tx + 16 * i];
#pragma unroll
            for (int j4 = 0; j4 < TM / 4; ++j4) {
                float4 wv = *(const float4*)&Ws[k][ty * TM + j4 * 4];
                w[j4 * 4 + 0] = wv.x; w[j4 * 4 + 1] = wv.y;
                w[j4 * 4 + 2] = wv.z; w[j4 * 4 + 3] = wv.w;
            }
#pragma unroll
            for (int i = 0; i < TN; ++i)
#pragma unroll
                for (int j = 0; j < TM; ++j) acc[i][j] = fmaf(a[i], w[j], acc[i][j]);
        }
    }

#pragma unroll
    for (int i = 0; i < TN; ++i) {
        int node = nodeBase + tx + 16 * i;
        if (node < N) {
            float* cp = C + (size_t)node * M + foff + ty * TM;
#pragma unroll
            for (int j4 = 0; j4 < TM / 4; ++j4) {
                float t[4];
#pragma unroll
                for (int c = 0; c < 4; ++c) {
                    float x = acc[i][j4 * 4 + c];
                    if constexpr (BIAS) x += bias[foff + ty * TM + j4 * 4 + c];
                    if constexpr (ACT == 1) x = fmaxf(x, 0.f);
                    if constexpr (ACT == 2) x = 1.f / (1.f + __expf(-x));
                    t[c] = x;
                }
                float4 v; v.x = t[0]; v.y = t[1]; v.z = t[2]; v.w = t[3];
                *(float4*)(cp + j4 * 4) = v;
            }
        }
    }
}

// ---------------- CSR build: deterministic counting sort -------------
// bucket b = dst >> 6 (64 dsts/bucket, NB buckets).
// cnt/pos index = (b*8 + r)*GRP + g, where blk = g*8... actually r=blk&7
// (XCD residue under round-robin dispatch), g = blk>>3.

// per-block LDS histogram over buckets -> cnt
__global__ __launch_bounds__(256) void count_k(const int* __restrict__ ei,
                                               int* __restrict__ cnt,
                                               int NB, int E) {
    __shared__ int hist[784];
    const int tid = threadIdx.x;
    for (int i = tid; i < NB; i += 256) hist[i] = 0;
    __syncthreads();
    const int chunk = (E + NBLK - 1) / NBLK;
    const int lo = blockIdx.x * chunk;
    const int hi = min(lo + chunk, E);
    for (int e = lo + tid; e < hi; e += 256) {
        int d = ei[E + e];
        atomicAdd(&hist[d >> 6], 1);
    }
    __syncthreads();
    const int r = blockIdx.x & 7, g = blockIdx.x >> 3;
    for (int i = tid; i < NB; i += 256)
        cnt[(i * 8 + r) * GRP + g] = hist[i];
}

// single-block exclusive scan over n = NB*NBLK counts
__global__ __launch_bounds__(256) void scan_k(const int* __restrict__ cnt,
                                              int* __restrict__ pos,
                                              int* __restrict__ bucketBase,
                                              int NB, int E) {
    __shared__ int s[256];
    const int n = NB * NBLK;
    const int t = threadIdx.x;
    const int chunk = (n + 255) / 256;
    const int lo = t * chunk, hi = min(lo + chunk, n);
    int sum = 0;
    for (int i = lo; i < hi; ++i) sum += cnt[i];
    s[t] = sum;
    __syncthreads();
    for (int off = 1; off < 256; off <<= 1) {
        int v = (t >= off) ? s[t - off] : 0;
        __syncthreads();
        s[t] += v;
        __syncthreads();
    }
    int running = s[t] - sum;  // exclusive
    for (int i = lo; i < hi; ++i) {
        pos[i] = running;
        if ((i & (NBLK - 1)) == 0) bucketBase[i / NBLK] = running;
        running += cnt[i];
    }
    if (t == 0) bucketBase[NB] = E;
}

// replay edges; LDS cursors only (no global atomics); payload {src|dl<<26, w}
__global__ __launch_bounds__(256) void place_k(const int* __restrict__ ei,
                                               const float* __restrict__ w,
                                               const int* __restrict__ pos,
                                               int2* __restrict__ ebuf,
                                               int NB, int E) {
    __shared__ int cur[784];
    const int tid = threadIdx.x;
    const int r = blockIdx.x & 7, g = blockIdx.x >> 3;
    for (int i = tid; i < NB; i += 256) cur[i] = pos[(i * 8 + r) * GRP + g];
    __syncthreads();
    const int chunk = (E + NBLK - 1) / NBLK;
    const int lo = blockIdx.x * chunk;
    const int hi = min(lo + chunk, E);
    for (int e = lo + tid; e < hi; e += 256) {
        int s = ei[e];
        int d = ei[E + e];
        float wv = w[e];
        int p = atomicAdd(&cur[d >> 6], 1);  // LDS atomic
        ebuf[p] = make_int2(s | ((d & 63) << 26), __float_as_int(wv));
    }
}

// one block per bucket: LDS hist over 64 local dsts -> row/dinv + ordered sn
__global__ __launch_bounds__(256) void bucket_build(const int2* __restrict__ ebuf,
                                                    const int* __restrict__ bucketBase,
                                                    int2* __restrict__ sn,
                                                    int* __restrict__ row,
                                                    float* __restrict__ dinv,
                                                    int N, int E) {
    __shared__ int   lh[64];
    __shared__ float ldg[64];
    __shared__ int   sc[64];
    __shared__ int   lofs[64];
    const int tid  = threadIdx.x;
    const int base = bucketBase[blockIdx.x];
    const int end  = bucketBase[blockIdx.x + 1];

    if (tid < 64) { lh[tid] = 0; ldg[tid] = 0.f; }
    __syncthreads();
    for (int i = base + tid; i < end; i += 256) {
        int2 v = ebuf[i];
        int dl = ((unsigned)v.x) >> 26;
        atomicAdd(&lh[dl], 1);
        atomicAdd(&ldg[dl], __int_as_float(v.y));
    }
    __syncthreads();
    if (tid < 64) sc[tid] = lh[tid];
    __syncthreads();
    for (int off = 1; off < 64; off <<= 1) {
        int v = (tid < 64 && tid >= off) ? sc[tid - off] : 0;
        __syncthreads();
        if (tid < 64) sc[tid] += v;
        __syncthreads();
    }
    if (tid < 64) {
        int excl = sc[tid] - lh[tid];
        int d = (blockIdx.x << 6) + tid;
        if (d < N) {
            row[d]  = base + excl;
            dinv[d] = rsqrtf(fmaxf(1.0f + ldg[tid], 1e-12f));  // + self-loop
        }
        lofs[tid] = base + excl;
    }
    __syncthreads();
    for (int i = base + tid; i < end; i += 256) {
        int2 v = ebuf[i];
        unsigned u = (unsigned)v.x;
        int dl = u >> 26;
        int s  = u & 0x03FFFFFF;
        int p  = atomicAdd(&lofs[dl], 1);
        sn[p] = make_int2(s, v.y);
    }
    if (blockIdx.x == 0 && tid == 0) row[N] = E;
}

// payload.y <- w * dinv[src]
__global__ __launch_bounds__(256) void scale_pay(int2* __restrict__ sn,
                                                 const float* __restrict__ dinv,
                                                 int E) {
    int p = blockIdx.x * 256 + threadIdx.x;
    if (p < E) {
        int2 v = sn[p];
        sn[p] = make_int2(v.x, __float_as_int(__int_as_float(v.y) * dinv[v.x]));
    }
}

// ---------------- fused GCN aggregation (gather, no atomics) ---------
// out[i] = relu( (sum_e pay_e*t[src_e] + t[i]*dinv[i]) * dinv[i] + b )
__global__ __launch_bounds__(256) void gcn_agg(const float* __restrict__ t,
                                               const int2* __restrict__ sn,
                                               const int* __restrict__ row,
                                               const float* __restrict__ dinv,
                                               const float* __restrict__ bias,
                                               float* __restrict__ out, int N) {
    const int lane = threadIdx.x & 63;
    int i = __builtin_amdgcn_readfirstlane((int)(blockIdx.x * 4) + (threadIdx.x >> 6));
    if (i >= N) return;
    float di   = dinv[i];
    float self = t[(size_t)i * 64 + lane];
    float acc  = 0.f;
    int p  = row[i];
    int pe = row[i + 1];
    for (; p + 4 <= pe; p += 4) {
        int2 v0 = sn[p];
        int2 v1 = sn[p + 1];
        int2 v2 = sn[p + 2];
        int2 v3 = sn[p + 3];
        acc += t[(size_t)v0.x * 64 + lane] * __int_as_float(v0.y);
        acc += t[(size_t)v1.x * 64 + lane] * __int_as_float(v1.y);
        acc += t[(size_t)v2.x * 64 + lane] * __int_as_float(v2.y);
        acc += t[(size_t)v3.x * 64 + lane] * __int_as_float(v3.y);
    }
    for (; p < pe; ++p) {
        int2 v = sn[p];
        acc += t[(size_t)v.x * 64 + lane] * __int_as_float(v.y);
    }
    float x = (acc + self * di) * di + bias[lane];
    out[(size_t)i * 64 + lane] = fmaxf(x, 0.f);
}

// =====================================================================
extern "C" void kernel_launch(void* const* d_in, const int* in_sizes, int n_in,
                              void* d_out, int out_size, void* d_ws, size_t ws_size,
                              hipStream_t stream) {
    const float* x      = (const float*)d_in[0];
    const int*   ei     = (const int*)d_in[1];   // int32 per harness contract
    const float* ew     = (const float*)d_in[2];
    const float* enc1_w = (const float*)d_in[3];
    const float* enc1_b = (const float*)d_in[4];
    const float* enc2_w = (const float*)d_in[5];
    const float* enc2_b = (const float*)d_in[6];
    const float* gcn1_w = (const float*)d_in[7];
    const float* gcn1_b = (const float*)d_in[8];
    const float* gcn2_w = (const float*)d_in[9];
    const float* gcn2_b = (const float*)d_in[10];
    const float* dec1_w = (const float*)d_in[11];
    const float* dec1_b = (const float*)d_in[12];
    const float* dec2_w = (const float*)d_in[13];
    const float* dec2_b = (const float*)d_in[14];

    const int N  = in_sizes[0] / 256;   // 50000
    const int E  = in_sizes[2];         // 1600000
    const int NB = (N + 63) / 64;       // 782 buckets

    // workspace (~40 MB):
    //  bufA [N*128 floats]: h1 -> { sn[E] int2 | ebuf[E] int2 (=bufC) } -> h5
    //  bufB [N*64]: h2/h3/h4 ; dinv[N]; row[N+1];
    //  cnt[NB*NBLK]; pos[NB*NBLK]; bucketBase[NB+1]
    float* ws   = (float*)d_ws;
    float* bufA = ws;
    int2*  sn   = (int2*)bufA;                  // E int2 (first half of bufA)
    float* bufC = bufA + (size_t)2 * E;         // N*64 floats (second half)
    int2*  ebuf = (int2*)bufC;                  // aliases bufC during build
    float* bufB = bufA + (size_t)N * 128;       // N*64
    float* dinv = bufB + (size_t)N * 64;        // N
    int*   row  = (int*)(dinv + N);             // N+1
    int*   cnt  = row + (N + 1);                // NB*NBLK
    int*   pos  = cnt + NB * NBLK;              // NB*NBLK
    int*   bucketBase = pos + NB * NBLK;        // NB+1

    const int gemmGrid = (N + 127) / 128;       // 391
    const int nBlkE    = (E + 255) / 256;       // 6250

    // encoder
    gemm_rt<256, 128, 128, 1, true><<<dim3(gemmGrid, 1), 256, 0, stream>>>(
        x, enc1_w, enc1_b, bufA, N);
    gemm_rt<128, 64, 64, 1, true><<<dim3(gemmGrid, 1), 256, 0, stream>>>(
        bufA, enc2_w, enc2_b, bufB, N);

    // CSR build, zero global atomics (shared by both GCN layers)
    count_k<<<NBLK, 256, 0, stream>>>(ei, cnt, NB, E);
    scan_k<<<1, 256, 0, stream>>>(cnt, pos, bucketBase, NB, E);
    place_k<<<NBLK, 256, 0, stream>>>(ei, ew, pos, ebuf, NB, E);
    bucket_build<<<NB, 256, 0, stream>>>(ebuf, bucketBase, sn, row, dinv, N, E);
    scale_pay<<<nBlkE, 256, 0, stream>>>(sn, dinv, E);

    // GCN layer 1
    gemm_rt<64, 64, 64, 0, false><<<dim3(gemmGrid, 1), 256, 0, stream>>>(
        bufB, gcn1_w, nullptr, bufC, N);
    gcn_agg<<<(N + 3) / 4, 256, 0, stream>>>(bufC, sn, row, dinv, gcn1_b, bufB, N);

    // GCN layer 2
    gemm_rt<64, 64, 64, 0, false><<<dim3(gemmGrid, 1), 256, 0, stream>>>(
        bufB, gcn2_w, nullptr, bufC, N);
    gcn_agg<<<(N + 3) / 4, 256, 0, stream>>>(bufC, sn, row, dinv, gcn2_b, bufB, N);

    // decoder
    gemm_rt<64, 128, 128, 1, true><<<dim3(gemmGrid, 1), 256, 0, stream>>>(
        bufB, dec1_w, dec1_b, bufA, N);
    gemm_rt<128, 128, 256, 2, true><<<dim3(gemmGrid, 2), 256, 0, stream>>>(
        bufA, dec2_w, dec2_b, (float*)d_out, N);
}

// Round 8
// 525.135 us; speedup vs baseline: 1.2916x; 1.2916x over previous
//
#include <hip/hip_runtime.h>

// =====================================================================
// GraphAutoEncoder forward (all fp32). GCN via CSR build + gather.
// R3: register-tiled fp32 GEMM. R7: zero-global-atomic counting-sort CSR
// build (place_k/count_k confirmed cheap). R8: the R7 regression was
// scan_k — a SINGLE block serially scanning 100K counts (167 us, one CU).
// Replaced with 3-kernel parallel scan (196 blocks x 512 + tops + add).
// =====================================================================

constexpr int NBLK = 128;           // scatter blocks (chunk = E/128)
constexpr int GRP  = NBLK / 8;      // block-groups per XCD residue

// ---------------- GEMM: C[:,foff:foff+MT] = act(A @ W^T + b) ---------
template <int K, int MT, int M, int ACT, bool BIAS>  // ACT: 0 none,1 relu,2 sigmoid
__global__ __launch_bounds__(256) void gemm_rt(const float* __restrict__ A,
                                               const float* __restrict__ W,
                                               const float* __restrict__ bias,
                                               float* __restrict__ C, int N) {
    constexpr int KC = 32;
    constexpr int TM = MT / 16;
    constexpr int TN = 8;
    __shared__ float As[KC][128 + 4];
    __shared__ float Ws[KC][MT + 4];

    const int tid  = threadIdx.x;
    const int tx   = tid & 15;
    const int ty   = tid >> 4;
    const int nodeBase = blockIdx.x * 128;
    const int foff     = blockIdx.y * MT;

    float acc[TN][TM];
#pragma unroll
    for (int i = 0; i < TN; ++i)
#pragma unroll
        for (int j = 0; j < TM; ++j) acc[i][j] = 0.f;

    for (int kc = 0; kc < K; kc += KC) {
        __syncthreads();
#pragma unroll
        for (int i = 0; i < 4; ++i) {
            int f  = tid + 256 * i;
            int n  = f >> 3;
            int k4 = f & 7;
            int gn = nodeBase + n;
            float4 v = make_float4(0.f, 0.f, 0.f, 0.f);
            if (gn < N) v = *(const float4*)(A + (size_t)gn * K + kc + k4 * 4);
            As[k4 * 4 + 0][n] = v.x;
            As[k4 * 4 + 1][n] = v.y;
            As[k4 * 4 + 2][n] = v.z;
            As[k4 * 4 + 3][n] = v.w;
        }
#pragma unroll
        for (int i = 0; i < MT / 32; ++i) {
            int f  = tid + 256 * i;
            int m  = f >> 3;
            int k4 = f & 7;
            float4 v = *(const float4*)(W + (size_t)(foff + m) * K + kc + k4 * 4);
            Ws[k4 * 4 + 0][m] = v.x;
            Ws[k4 * 4 + 1][m] = v.y;
            Ws[k4 * 4 + 2][m] = v.z;
            Ws[k4 * 4 + 3][m] = v.w;
        }
        __syncthreads();
#pragma unroll 4
        for (int k = 0; k < KC; ++k) {
            float a[TN];
            float w[TM];
#pragma unroll
            for (int i = 0; i < TN; ++i) a[i] = As[k][tx + 16 * i];
#pragma unroll
            for (int j4 = 0; j4 < TM / 4; ++j4) {
                float4 wv = *(const float4*)&Ws[k][ty * TM + j4 * 4];
                w[j4 * 4 + 0] = wv.x; w[j4 * 4 + 1] = wv.y;
                w[j4 * 4 + 2] = wv.z; w[j4 * 4 + 3] = wv.w;
            }
#pragma unroll
            for (int i = 0; i < TN; ++i)
#pragma unroll
                for (int j = 0; j < TM; ++j) acc[i][j] = fmaf(a[i], w[j], acc[i][j]);
        }
    }

#pragma unroll
    for (int i = 0; i < TN; ++i) {
        int node = nodeBase + tx + 16 * i;
        if (node < N) {
            float* cp = C + (size_t)node * M + foff + ty * TM;
#pragma unroll
            for (int j4 = 0; j4 < TM / 4; ++j4) {
                float t[4];
#pragma unroll
                for (int c = 0; c < 4; ++c) {
                    float x = acc[i][j4 * 4 + c];
                    if constexpr (BIAS) x += bias[foff + ty * TM + j4 * 4 + c];
                    if constexpr (ACT == 1) x = fmaxf(x, 0.f);
                    if constexpr (ACT == 2) x = 1.f / (1.f + __expf(-x));
                    t[c] = x;
                }
                float4 v; v.x = t[0]; v.y = t[1]; v.z = t[2]; v.w = t[3];
                *(float4*)(cp + j4 * 4) = v;
            }
        }
    }
}

// ---------------- CSR build: deterministic counting sort -------------
// bucket b = dst >> 6 (64 dsts/bucket, NB buckets).
// count index = b*128 + r*16 + g  (r = blockIdx&7 = XCD residue, g = blockIdx>>3)
// => bucketBase[b] = pos[b*128].

// per-block LDS histogram over buckets -> cnt
__global__ __launch_bounds__(256) void count_k(const int* __restrict__ ei,
                                               int* __restrict__ cnt,
                                               int NB, int E) {
    __shared__ int hist[784];
    const int tid = threadIdx.x;
    for (int i = tid; i < NB; i += 256) hist[i] = 0;
    __syncthreads();
    const int chunk = (E + NBLK - 1) / NBLK;
    const int lo = blockIdx.x * chunk;
    const int hi = min(lo + chunk, E);
    for (int e = lo + tid; e < hi; e += 256) {
        int d = ei[E + e];
        atomicAdd(&hist[d >> 6], 1);
    }
    __syncthreads();
    const int r = blockIdx.x & 7, g = blockIdx.x >> 3;
    for (int i = tid; i < NB; i += 256)
        cnt[i * NBLK + r * GRP + g] = hist[i];
}

// parallel scan, stage 1: 512 elements per block, exclusive within block
__global__ __launch_bounds__(256) void scan1(const int* __restrict__ cnt,
                                             int* __restrict__ pos,
                                             int* __restrict__ bs, int n) {
    __shared__ int s[256];
    const int t = threadIdx.x;
    const int i0 = blockIdx.x * 512 + 2 * t;
    int c0 = (i0     < n) ? cnt[i0]     : 0;
    int c1 = (i0 + 1 < n) ? cnt[i0 + 1] : 0;
    int c = c0 + c1;
    s[t] = c;
    __syncthreads();
    for (int off = 1; off < 256; off <<= 1) {
        int v = (t >= off) ? s[t - off] : 0;
        __syncthreads();
        s[t] += v;
        __syncthreads();
    }
    int excl = s[t] - c;
    if (i0     < n) pos[i0]     = excl;
    if (i0 + 1 < n) pos[i0 + 1] = excl + c0;
    if (t == 255) bs[blockIdx.x] = s[255];
}

// stage 2: exclusive scan of block sums (nb <= 256), in place
__global__ __launch_bounds__(256) void scan_tops(int* __restrict__ bs, int nb) {
    __shared__ int s[256];
    int t = threadIdx.x;
    int v = (t < nb) ? bs[t] : 0;
    s[t] = v;
    __syncthreads();
    for (int off = 1; off < 256; off <<= 1) {
        int u = (t >= off) ? s[t - off] : 0;
        __syncthreads();
        s[t] += u;
        __syncthreads();
    }
    if (t < nb) bs[t] = s[t] - v;
}

// stage 3: add block offsets; extract bucketBase at stride-128 positions
__global__ __launch_bounds__(256) void scan2(int* __restrict__ pos,
                                             const int* __restrict__ bs,
                                             int* __restrict__ bucketBase,
                                             int n, int NB, int E) {
    const int t = threadIdx.x;
    const int i0 = blockIdx.x * 512 + 2 * t;
    const int add = bs[blockIdx.x];
#pragma unroll
    for (int c = 0; c < 2; ++c) {
        int i = i0 + c;
        if (i < n) {
            int v = pos[i] + add;
            pos[i] = v;
            if ((i & (NBLK - 1)) == 0) bucketBase[i >> 7] = v;
        }
    }
    if (blockIdx.x == 0 && t == 0) bucketBase[NB] = E;
}

// replay edges; LDS cursors only (no global atomics); payload {src|dl<<26, w}
__global__ __launch_bounds__(256) void place_k(const int* __restrict__ ei,
                                               const float* __restrict__ w,
                                               const int* __restrict__ pos,
                                               int2* __restrict__ ebuf,
                                               int NB, int E) {
    __shared__ int cur[784];
    const int tid = threadIdx.x;
    const int r = blockIdx.x & 7, g = blockIdx.x >> 3;
    for (int i = tid; i < NB; i += 256) cur[i] = pos[i * NBLK + r * GRP + g];
    __syncthreads();
    const int chunk = (E + NBLK - 1) / NBLK;
    const int lo = blockIdx.x * chunk;
    const int hi = min(lo + chunk, E);
    for (int e = lo + tid; e < hi; e += 256) {
        int s = ei[e];
        int d = ei[E + e];
        float wv = w[e];
        int p = atomicAdd(&cur[d >> 6], 1);  // LDS atomic
        ebuf[p] = make_int2(s | ((d & 63) << 26), __float_as_int(wv));
    }
}

// one block per bucket: LDS hist over 64 local dsts -> row/dinv + ordered sn
__global__ __launch_bounds__(256) void bucket_build(const int2* __restrict__ ebuf,
                                                    const int* __restrict__ bucketBase,
                                                    int2* __restrict__ sn,
                                                    int* __restrict__ row,
                                                    float* __restrict__ dinv,
                                                    int N, int E) {
    __shared__ int   lh[64];
    __shared__ float ldg[64];
    __shared__ int   sc[64];
    __shared__ int   lofs[64];
    const int tid  = threadIdx.x;
    const int base = bucketBase[blockIdx.x];
    const int end  = bucketBase[blockIdx.x + 1];

    if (tid < 64) { lh[tid] = 0; ldg[tid] = 0.f; }
    __syncthreads();
    for (int i = base + tid; i < end; i += 256) {
        int2 v = ebuf[i];
        int dl = ((unsigned)v.x) >> 26;
        atomicAdd(&lh[dl], 1);
        atomicAdd(&ldg[dl], __int_as_float(v.y));
    }
    __syncthreads();
    if (tid < 64) sc[tid] = lh[tid];
    __syncthreads();
    for (int off = 1; off < 64; off <<= 1) {
        int v = (tid < 64 && tid >= off) ? sc[tid - off] : 0;
        __syncthreads();
        if (tid < 64) sc[tid] += v;
        __syncthreads();
    }
    if (tid < 64) {
        int excl = sc[tid] - lh[tid];
        int d = (blockIdx.x << 6) + tid;
        if (d < N) {
            row[d]  = base + excl;
            dinv[d] = rsqrtf(fmaxf(1.0f + ldg[tid], 1e-12f));  // + self-loop
        }
        lofs[tid] = base + excl;
    }
    __syncthreads();
    for (int i = base + tid; i < end; i += 256) {
        int2 v = ebuf[i];
        unsigned u = (unsigned)v.x;
        int dl = u >> 26;
        int s  = u & 0x03FFFFFF;
        int p  = atomicAdd(&lofs[dl], 1);
        sn[p] = make_int2(s, v.y);
    }
    if (blockIdx.x == 0 && tid == 0) row[N] = E;
}

// payload.y <- w * dinv[src]
__global__ __launch_bounds__(256) void scale_pay(int2* __restrict__ sn,
                                                 const float* __restrict__ dinv,
                                                 int E) {
    int p = blockIdx.x * 256 + threadIdx.x;
    if (p < E) {
        int2 v = sn[p];
        sn[p] = make_int2(v.x, __float_as_int(__int_as_float(v.y) * dinv[v.x]));
    }
}

// ---------------- fused GCN aggregation (gather, no atomics) ---------
// out[i] = relu( (sum_e pay_e*t[src_e] + t[i]*dinv[i]) * dinv[i] + b )
__global__ __launch_bounds__(256) void gcn_agg(const float* __restrict__ t,
                                               const int2* __restrict__ sn,
                                               const int* __restrict__ row,
                                               const float* __restrict__ dinv,
                                               const float* __restrict__ bias,
                                               float* __restrict__ out, int N) {
    const int lane = threadIdx.x & 63;
    int i = __builtin_amdgcn_readfirstlane((int)(blockIdx.x * 4) + (threadIdx.x >> 6));
    if (i >= N) return;
    float di   = dinv[i];
    float self = t[(size_t)i * 64 + lane];
    float acc  = 0.f;
    int p  = row[i];
    int pe = row[i + 1];
    for (; p + 4 <= pe; p += 4) {
        int2 v0 = sn[p];
        int2 v1 = sn[p + 1];
        int2 v2 = sn[p + 2];
        int2 v3 = sn[p + 3];
        acc += t[(size_t)v0.x * 64 + lane] * __int_as_float(v0.y);
        acc += t[(size_t)v1.x * 64 + lane] * __int_as_float(v1.y);
        acc += t[(size_t)v2.x * 64 + lane] * __int_as_float(v2.y);
        acc += t[(size_t)v3.x * 64 + lane] * __int_as_float(v3.y);
    }
    for (; p < pe; ++p) {
        int2 v = sn[p];
        acc += t[(size_t)v.x * 64 + lane] * __int_as_float(v.y);
    }
    float x = (acc + self * di) * di + bias[lane];
    out[(size_t)i * 64 + lane] = fmaxf(x, 0.f);
}

// =====================================================================
extern "C" void kernel_launch(void* const* d_in, const int* in_sizes, int n_in,
                              void* d_out, int out_size, void* d_ws, size_t ws_size,
                              hipStream_t stream) {
    const float* x      = (const float*)d_in[0];
    const int*   ei     = (const int*)d_in[1];   // int32 per harness contract
    const float* ew     = (const float*)d_in[2];
    const float* enc1_w = (const float*)d_in[3];
    const float* enc1_b = (const float*)d_in[4];
    const float* enc2_w = (const float*)d_in[5];
    const float* enc2_b = (const float*)d_in[6];
    const float* gcn1_w = (const float*)d_in[7];
    const float* gcn1_b = (const float*)d_in[8];
    const float* gcn2_w = (const float*)d_in[9];
    const float* gcn2_b = (const float*)d_in[10];
    const float* dec1_w = (const float*)d_in[11];
    const float* dec1_b = (const float*)d_in[12];
    const float* dec2_w = (const float*)d_in[13];
    const float* dec2_b = (const float*)d_in[14];

    const int N  = in_sizes[0] / 256;   // 50000
    const int E  = in_sizes[2];         // 1600000
    const int NB = (N + 63) / 64;       // 782 buckets
    const int NCNT = NB * NBLK;         // 100096 counters
    const int NS   = (NCNT + 511) / 512; // 196 scan blocks

    // workspace (~40 MB):
    //  bufA [N*128 floats]: h1 -> { sn[E] int2 | ebuf[E] int2 (=bufC) } -> h5
    //  bufB [N*64]: h2/h3/h4 ; dinv[N]; row[N+1];
    //  cnt[NCNT]; pos[NCNT]; bucketBase[NB+1]; bs[256]
    float* ws   = (float*)d_ws;
    float* bufA = ws;
    int2*  sn   = (int2*)bufA;                  // E int2 (first half of bufA)
    float* bufC = bufA + (size_t)2 * E;         // N*64 floats (second half)
    int2*  ebuf = (int2*)bufC;                  // aliases bufC during build
    float* bufB = bufA + (size_t)N * 128;       // N*64
    float* dinv = bufB + (size_t)N * 64;        // N
    int*   row  = (int*)(dinv + N);             // N+1
    int*   cnt  = row + (N + 1);                // NCNT
    int*   pos  = cnt + NCNT;                   // NCNT
    int*   bucketBase = pos + NCNT;             // NB+1
    int*   bs   = bucketBase + (NB + 1);        // 256

    const int gemmGrid = (N + 127) / 128;       // 391
    const int nBlkE    = (E + 255) / 256;       // 6250

    // encoder
    gemm_rt<256, 128, 128, 1, true><<<dim3(gemmGrid, 1), 256, 0, stream>>>(
        x, enc1_w, enc1_b, bufA, N);
    gemm_rt<128, 64, 64, 1, true><<<dim3(gemmGrid, 1), 256, 0, stream>>>(
        bufA, enc2_w, enc2_b, bufB, N);

    // CSR build, zero global atomics (shared by both GCN layers)
    count_k<<<NBLK, 256, 0, stream>>>(ei, cnt, NB, E);
    scan1<<<NS, 256, 0, stream>>>(cnt, pos, bs, NCNT);
    scan_tops<<<1, 256, 0, stream>>>(bs, NS);
    scan2<<<NS, 256, 0, stream>>>(pos, bs, bucketBase, NCNT, NB, E);
    place_k<<<NBLK, 256, 0, stream>>>(ei, ew, pos, ebuf, NB, E);
    bucket_build<<<NB, 256, 0, stream>>>(ebuf, bucketBase, sn, row, dinv, N, E);
    scale_pay<<<nBlkE, 256, 0, stream>>>(sn, dinv, E);

    // GCN layer 1
    gemm_rt<64, 64, 64, 0, false><<<dim3(gemmGrid, 1), 256, 0, stream>>>(
        bufB, gcn1_w, nullptr, bufC, N);
    gcn_agg<<<(N + 3) / 4, 256, 0, stream>>>(bufC, sn, row, dinv, gcn1_b, bufB, N);

    // GCN layer 2
    gemm_rt<64, 64, 64, 0, false><<<dim3(gemmGrid, 1), 256, 0, stream>>>(
        bufB, gcn2_w, nullptr, bufC, N);
    gcn_agg<<<(N + 3) / 4, 256, 0, stream>>>(bufC, sn, row, dinv, gcn2_b, bufB, N);

    // decoder
    gemm_rt<64, 128, 128, 1, true><<<dim3(gemmGrid, 1), 256, 0, stream>>>(
        bufB, dec1_w, dec1_b, bufA, N);
    gemm_rt<128, 128, 256, 2, true><<<dim3(gemmGrid, 2), 256, 0, stream>>>(
        bufA, dec2_w, dec2_b, (float*)d_out, N);
}

// Round 9
// 497.694 us; speedup vs baseline: 1.3629x; 1.0551x over previous
//
#include <hip/hip_runtime.h>

// =====================================================================
// GraphAutoEncoder forward (all fp32). GCN via CSR build + gather.
// R8: parallel scan fixed the build chain. R9: big GEMMs were
// GRID-WIDTH-limited (391 blocks / 256 CUs = 1.5 blocks/CU, occupancy
// 12.5%, VALUBusy 32%). Node tile 128->64 and KC 32->16: enc1 782
// blocks (~3/CU), dec2 1564 (~6/CU); LDS 33.8K -> 8.7-12.8K.
// =====================================================================

constexpr int NBLK = 128;           // scatter blocks (chunk = E/128)
constexpr int GRP  = NBLK / 8;      // block-groups per XCD residue

// ---------------- GEMM: C[:,foff:foff+MT] = act(A @ W^T + b) ---------
// node tile = 64 (TN=4, stride 16), KC=16, MT per blockIdx.y.
template <int K, int MT, int M, int ACT, bool BIAS>  // ACT: 0 none,1 relu,2 sigmoid
__global__ __launch_bounds__(256) void gemm_rt(const float* __restrict__ A,
                                               const float* __restrict__ W,
                                               const float* __restrict__ bias,
                                               float* __restrict__ C, int N) {
    constexpr int KC = 16;
    constexpr int NT = 64;
    constexpr int TM = MT / 16;   // 8 (MT=128) or 4 (MT=64)
    constexpr int TN = 4;
    __shared__ float As[KC][NT + 4];
    __shared__ float Ws[KC][MT + 4];

    const int tid  = threadIdx.x;
    const int tx   = tid & 15;
    const int ty   = tid >> 4;
    const int nodeBase = blockIdx.x * NT;
    const int foff     = blockIdx.y * MT;

    float acc[TN][TM];
#pragma unroll
    for (int i = 0; i < TN; ++i)
#pragma unroll
        for (int j = 0; j < TM; ++j) acc[i][j] = 0.f;

    for (int kc = 0; kc < K; kc += KC) {
        __syncthreads();
        // stage A[nodeBase..+64][kc..kc+16] transposed: 256 float4, 1/thread
        {
            int n  = tid >> 2;        // 0..63
            int k4 = tid & 3;         // 0..3
            int gn = nodeBase + n;
            float4 v = make_float4(0.f, 0.f, 0.f, 0.f);
            if (gn < N) v = *(const float4*)(A + (size_t)gn * K + kc + k4 * 4);
            As[k4 * 4 + 0][n] = v.x;
            As[k4 * 4 + 1][n] = v.y;
            As[k4 * 4 + 2][n] = v.z;
            As[k4 * 4 + 3][n] = v.w;
        }
        // stage W[foff..foff+MT][kc..kc+16] transposed: MT*4 float4
#pragma unroll
        for (int i = 0; i < MT / 64; ++i) {
            int f  = tid + 256 * i;
            int m  = f >> 2;          // 0..MT-1
            int k4 = f & 3;
            float4 v = *(const float4*)(W + (size_t)(foff + m) * K + kc + k4 * 4);
            Ws[k4 * 4 + 0][m] = v.x;
            Ws[k4 * 4 + 1][m] = v.y;
            Ws[k4 * 4 + 2][m] = v.z;
            Ws[k4 * 4 + 3][m] = v.w;
        }
        __syncthreads();
#pragma unroll 4
        for (int k = 0; k < KC; ++k) {
            float a[TN];
            float w[TM];
#pragma unroll
            for (int i = 0; i < TN; ++i) a[i] = As[k][tx + 16 * i];  // 2-way = free
#pragma unroll
            for (int j4 = 0; j4 < TM / 4; ++j4) {
                float4 wv = *(const float4*)&Ws[k][ty * TM + j4 * 4];  // broadcast
                w[j4 * 4 + 0] = wv.x; w[j4 * 4 + 1] = wv.y;
                w[j4 * 4 + 2] = wv.z; w[j4 * 4 + 3] = wv.w;
            }
#pragma unroll
            for (int i = 0; i < TN; ++i)
#pragma unroll
                for (int j = 0; j < TM; ++j) acc[i][j] = fmaf(a[i], w[j], acc[i][j]);
        }
    }

#pragma unroll
    for (int i = 0; i < TN; ++i) {
        int node = nodeBase + tx + 16 * i;
        if (node < N) {
            float* cp = C + (size_t)node * M + foff + ty * TM;
#pragma unroll
            for (int j4 = 0; j4 < TM / 4; ++j4) {
                float t[4];
#pragma unroll
                for (int c = 0; c < 4; ++c) {
                    float x = acc[i][j4 * 4 + c];
                    if constexpr (BIAS) x += bias[foff + ty * TM + j4 * 4 + c];
                    if constexpr (ACT == 1) x = fmaxf(x, 0.f);
                    if constexpr (ACT == 2) x = 1.f / (1.f + __expf(-x));
                    t[c] = x;
                }
                float4 v; v.x = t[0]; v.y = t[1]; v.z = t[2]; v.w = t[3];
                *(float4*)(cp + j4 * 4) = v;
            }
        }
    }
}

// ---------------- CSR build: deterministic counting sort -------------
// bucket b = dst >> 6; count index = b*128 + r*16 + g  (r = blockIdx&7,
// g = blockIdx>>3) => bucketBase[b] = pos[b*128]. Zero global atomics.

__global__ __launch_bounds__(256) void count_k(const int* __restrict__ ei,
                                               int* __restrict__ cnt,
                                               int NB, int E) {
    __shared__ int hist[784];
    const int tid = threadIdx.x;
    for (int i = tid; i < NB; i += 256) hist[i] = 0;
    __syncthreads();
    const int chunk = (E + NBLK - 1) / NBLK;
    const int lo = blockIdx.x * chunk;
    const int hi = min(lo + chunk, E);
    for (int e = lo + tid; e < hi; e += 256) {
        int d = ei[E + e];
        atomicAdd(&hist[d >> 6], 1);
    }
    __syncthreads();
    const int r = blockIdx.x & 7, g = blockIdx.x >> 3;
    for (int i = tid; i < NB; i += 256)
        cnt[i * NBLK + r * GRP + g] = hist[i];
}

__global__ __launch_bounds__(256) void scan1(const int* __restrict__ cnt,
                                             int* __restrict__ pos,
                                             int* __restrict__ bs, int n) {
    __shared__ int s[256];
    const int t = threadIdx.x;
    const int i0 = blockIdx.x * 512 + 2 * t;
    int c0 = (i0     < n) ? cnt[i0]     : 0;
    int c1 = (i0 + 1 < n) ? cnt[i0 + 1] : 0;
    int c = c0 + c1;
    s[t] = c;
    __syncthreads();
    for (int off = 1; off < 256; off <<= 1) {
        int v = (t >= off) ? s[t - off] : 0;
        __syncthreads();
        s[t] += v;
        __syncthreads();
    }
    int excl = s[t] - c;
    if (i0     < n) pos[i0]     = excl;
    if (i0 + 1 < n) pos[i0 + 1] = excl + c0;
    if (t == 255) bs[blockIdx.x] = s[255];
}

__global__ __launch_bounds__(256) void scan_tops(int* __restrict__ bs, int nb) {
    __shared__ int s[256];
    int t = threadIdx.x;
    int v = (t < nb) ? bs[t] : 0;
    s[t] = v;
    __syncthreads();
    for (int off = 1; off < 256; off <<= 1) {
        int u = (t >= off) ? s[t - off] : 0;
        __syncthreads();
        s[t] += u;
        __syncthreads();
    }
    if (t < nb) bs[t] = s[t] - v;
}

__global__ __launch_bounds__(256) void scan2(int* __restrict__ pos,
                                             const int* __restrict__ bs,
                                             int* __restrict__ bucketBase,
                                             int n, int NB, int E) {
    const int t = threadIdx.x;
    const int i0 = blockIdx.x * 512 + 2 * t;
    const int add = bs[blockIdx.x];
#pragma unroll
    for (int c = 0; c < 2; ++c) {
        int i = i0 + c;
        if (i < n) {
            int v = pos[i] + add;
            pos[i] = v;
            if ((i & (NBLK - 1)) == 0) bucketBase[i >> 7] = v;
        }
    }
    if (blockIdx.x == 0 && t == 0) bucketBase[NB] = E;
}

__global__ __launch_bounds__(256) void place_k(const int* __restrict__ ei,
                                               const float* __restrict__ w,
                                               const int* __restrict__ pos,
                                               int2* __restrict__ ebuf,
                                               int NB, int E) {
    __shared__ int cur[784];
    const int tid = threadIdx.x;
    const int r = blockIdx.x & 7, g = blockIdx.x >> 3;
    for (int i = tid; i < NB; i += 256) cur[i] = pos[i * NBLK + r * GRP + g];
    __syncthreads();
    const int chunk = (E + NBLK - 1) / NBLK;
    const int lo = blockIdx.x * chunk;
    const int hi = min(lo + chunk, E);
    for (int e = lo + tid; e < hi; e += 256) {
        int s = ei[e];
        int d = ei[E + e];
        float wv = w[e];
        int p = atomicAdd(&cur[d >> 6], 1);  // LDS atomic
        ebuf[p] = make_int2(s | ((d & 63) << 26), __float_as_int(wv));
    }
}

__global__ __launch_bounds__(256) void bucket_build(const int2* __restrict__ ebuf,
                                                    const int* __restrict__ bucketBase,
                                                    int2* __restrict__ sn,
                                                    int* __restrict__ row,
                                                    float* __restrict__ dinv,
                                                    int N, int E) {
    __shared__ int   lh[64];
    __shared__ float ldg[64];
    __shared__ int   sc[64];
    __shared__ int   lofs[64];
    const int tid  = threadIdx.x;
    const int base = bucketBase[blockIdx.x];
    const int end  = bucketBase[blockIdx.x + 1];

    if (tid < 64) { lh[tid] = 0; ldg[tid] = 0.f; }
    __syncthreads();
    for (int i = base + tid; i < end; i += 256) {
        int2 v = ebuf[i];
        int dl = ((unsigned)v.x) >> 26;
        atomicAdd(&lh[dl], 1);
        atomicAdd(&ldg[dl], __int_as_float(v.y));
    }
    __syncthreads();
    if (tid < 64) sc[tid] = lh[tid];
    __syncthreads();
    for (int off = 1; off < 64; off <<= 1) {
        int v = (tid < 64 && tid >= off) ? sc[tid - off] : 0;
        __syncthreads();
        if (tid < 64) sc[tid] += v;
        __syncthreads();
    }
    if (tid < 64) {
        int excl = sc[tid] - lh[tid];
        int d = (blockIdx.x << 6) + tid;
        if (d < N) {
            row[d]  = base + excl;
            dinv[d] = rsqrtf(fmaxf(1.0f + ldg[tid], 1e-12f));  // + self-loop
        }
        lofs[tid] = base + excl;
    }
    __syncthreads();
    for (int i = base + tid; i < end; i += 256) {
        int2 v = ebuf[i];
        unsigned u = (unsigned)v.x;
        int dl = u >> 26;
        int s  = u & 0x03FFFFFF;
        int p  = atomicAdd(&lofs[dl], 1);
        sn[p] = make_int2(s, v.y);
    }
    if (blockIdx.x == 0 && tid == 0) row[N] = E;
}

// payload.y <- w * dinv[src]
__global__ __launch_bounds__(256) void scale_pay(int2* __restrict__ sn,
                                                 const float* __restrict__ dinv,
                                                 int E) {
    int p = blockIdx.x * 256 + threadIdx.x;
    if (p < E) {
        int2 v = sn[p];
        sn[p] = make_int2(v.x, __float_as_int(__int_as_float(v.y) * dinv[v.x]));
    }
}

// ---------------- fused GCN aggregation (gather, no atomics) ---------
// out[i] = relu( (sum_e pay_e*t[src_e] + t[i]*dinv[i]) * dinv[i] + b )
__global__ __launch_bounds__(256) void gcn_agg(const float* __restrict__ t,
                                               const int2* __restrict__ sn,
                                               const int* __restrict__ row,
                                               const float* __restrict__ dinv,
                                               const float* __restrict__ bias,
                                               float* __restrict__ out, int N) {
    const int lane = threadIdx.x & 63;
    int i = __builtin_amdgcn_readfirstlane((int)(blockIdx.x * 4) + (threadIdx.x >> 6));
    if (i >= N) return;
    float di   = dinv[i];
    float self = t[(size_t)i * 64 + lane];
    float acc  = 0.f;
    int p  = row[i];
    int pe = row[i + 1];
    for (; p + 4 <= pe; p += 4) {
        int2 v0 = sn[p];
        int2 v1 = sn[p + 1];
        int2 v2 = sn[p + 2];
        int2 v3 = sn[p + 3];
        acc += t[(size_t)v0.x * 64 + lane] * __int_as_float(v0.y);
        acc += t[(size_t)v1.x * 64 + lane] * __int_as_float(v1.y);
        acc += t[(size_t)v2.x * 64 + lane] * __int_as_float(v2.y);
        acc += t[(size_t)v3.x * 64 + lane] * __int_as_float(v3.y);
    }
    for (; p < pe; ++p) {
        int2 v = sn[p];
        acc += t[(size_t)v.x * 64 + lane] * __int_as_float(v.y);
    }
    float x = (acc + self * di) * di + bias[lane];
    out[(size_t)i * 64 + lane] = fmaxf(x, 0.f);
}

// =====================================================================
extern "C" void kernel_launch(void* const* d_in, const int* in_sizes, int n_in,
                              void* d_out, int out_size, void* d_ws, size_t ws_size,
                              hipStream_t stream) {
    const float* x      = (const float*)d_in[0];
    const int*   ei     = (const int*)d_in[1];   // int32 per harness contract
    const float* ew     = (const float*)d_in[2];
    const float* enc1_w = (const float*)d_in[3];
    const float* enc1_b = (const float*)d_in[4];
    const float* enc2_w = (const float*)d_in[5];
    const float* enc2_b = (const float*)d_in[6];
    const float* gcn1_w = (const float*)d_in[7];
    const float* gcn1_b = (const float*)d_in[8];
    const float* gcn2_w = (const float*)d_in[9];
    const float* gcn2_b = (const float*)d_in[10];
    const float* dec1_w = (const float*)d_in[11];
    const float* dec1_b = (const float*)d_in[12];
    const float* dec2_w = (const float*)d_in[13];
    const float* dec2_b = (const float*)d_in[14];

    const int N  = in_sizes[0] / 256;    // 50000
    const int E  = in_sizes[2];          // 1600000
    const int NB = (N + 63) / 64;        // 782 buckets
    const int NCNT = NB * NBLK;          // 100096 counters
    const int NS   = (NCNT + 511) / 512; // 196 scan blocks

    // workspace (~40 MB):
    //  bufA [N*128 floats]: h1 -> { sn[E] int2 | ebuf[E] int2 (=bufC) } -> h5
    //  bufB [N*64]: h2/h3/h4 ; dinv[N]; row[N+1];
    //  cnt[NCNT]; pos[NCNT]; bucketBase[NB+1]; bs[256]
    float* ws   = (float*)d_ws;
    float* bufA = ws;
    int2*  sn   = (int2*)bufA;                  // E int2 (first half of bufA)
    float* bufC = bufA + (size_t)2 * E;         // N*64 floats (second half)
    int2*  ebuf = (int2*)bufC;                  // aliases bufC during build
    float* bufB = bufA + (size_t)N * 128;       // N*64
    float* dinv = bufB + (size_t)N * 64;        // N
    int*   row  = (int*)(dinv + N);             // N+1
    int*   cnt  = row + (N + 1);                // NCNT
    int*   pos  = cnt + NCNT;                   // NCNT
    int*   bucketBase = pos + NCNT;             // NB+1
    int*   bs   = bucketBase + (NB + 1);        // 256

    const int gemmGrid = (N + 63) / 64;         // 782
    const int nBlkE    = (E + 255) / 256;       // 6250

    // encoder
    gemm_rt<256, 128, 128, 1, true><<<dim3(gemmGrid, 1), 256, 0, stream>>>(
        x, enc1_w, enc1_b, bufA, N);
    gemm_rt<128, 64, 64, 1, true><<<dim3(gemmGrid, 1), 256, 0, stream>>>(
        bufA, enc2_w, enc2_b, bufB, N);

    // CSR build, zero global atomics (shared by both GCN layers)
    count_k<<<NBLK, 256, 0, stream>>>(ei, cnt, NB, E);
    scan1<<<NS, 256, 0, stream>>>(cnt, pos, bs, NCNT);
    scan_tops<<<1, 256, 0, stream>>>(bs, NS);
    scan2<<<NS, 256, 0, stream>>>(pos, bs, bucketBase, NCNT, NB, E);
    place_k<<<NBLK, 256, 0, stream>>>(ei, ew, pos, ebuf, NB, E);
    bucket_build<<<NB, 256, 0, stream>>>(ebuf, bucketBase, sn, row, dinv, N, E);
    scale_pay<<<nBlkE, 256, 0, stream>>>(sn, dinv, E);

    // GCN layer 1
    gemm_rt<64, 64, 64, 0, false><<<dim3(gemmGrid, 1), 256, 0, stream>>>(
        bufB, gcn1_w, nullptr, bufC, N);
    gcn_agg<<<(N + 3) / 4, 256, 0, stream>>>(bufC, sn, row, dinv, gcn1_b, bufB, N);

    // GCN layer 2
    gemm_rt<64, 64, 64, 0, false><<<dim3(gemmGrid, 1), 256, 0, stream>>>(
        bufB, gcn2_w, nullptr, bufC, N);
    gcn_agg<<<(N + 3) / 4, 256, 0, stream>>>(bufC, sn, row, dinv, gcn2_b, bufB, N);

    // decoder
    gemm_rt<64, 128, 128, 1, true><<<dim3(gemmGrid, 1), 256, 0, stream>>>(
        bufB, dec1_w, dec1_b, bufA, N);
    gemm_rt<128, 128, 256, 2, true><<<dim3(gemmGrid, 2), 256, 0, stream>>>(
        bufA, dec2_w, dec2_b, (float*)d_out, N);
}